// Round 9
// baseline (272.815 us; speedup 1.0000x reference)
//
#include <hip/hip_runtime.h>
#include <hip/hip_fp16.h>
#include <math.h>

// Problem constants (from reference): N=32, H=512, W=512, C=3, fp32 everywhere.
#define HH 512
#define WW 512
#define NNB 32
constexpr int PIXB = 256;                  // threads per block (4 waves)
constexpr int PIX = HH * WW;               // 262144 pixels per image
constexpr int IMG_ELEMS = PIX * 3;         // 786432 floats per [H,W,C] image
constexpr int NSPLIT = 4;                  // n-groups (blockIdx.y); 8 transforms per thread
constexpr int NPT = NNB / NSPLIT;          // transforms per thread loop
constexpr int PBLK = PIX / PIXB;           // 1024 pixel-blocks
constexpr int NPART = PBLK * NSPLIT;       // 4096 partials

// ---------------------------------------------------------------------------
// Prep: masked[p] = half4(mask*inter, pad 0).  fp16 halves the main kernel's
// tap L2 traffic (537 -> 268 MB), moving main from TCC-bound (~19us) to the
// HBM write floor (~16us).  fp16 abs err on |masked|<=0.6 is <=2.4e-4, 16x
// below the passing absmax 0.0039.  Also zeroes the finalize counter.
// ---------------------------------------------------------------------------
__global__ __launch_bounds__(256) void eot_prep(
    const float* __restrict__ mask, const float* __restrict__ inter,
    ushort4* __restrict__ masked, unsigned int* __restrict__ counter) {
  const int p = blockIdx.x * 256 + threadIdx.x;
  if (p == 0) *counter = 0;   // re-zeroed every call (ws is poisoned 0xAA)
  const int b = p * 3;
  ushort4 v;
  v.x = __half_as_ushort(__float2half_rn(mask[b] * inter[b]));
  v.y = __half_as_ushort(__float2half_rn(mask[b + 1] * inter[b + 1]));
  v.z = __half_as_ushort(__float2half_rn(mask[b + 2] * inter[b + 2]));
  v.w = 0;
  masked[p] = v;
}

// ---------------------------------------------------------------------------
// Main: thread per pixel, n-loop inside the thread (img/atanh amortized x8).
// Taps are single 8B dwordx2 loads from the fp16-padded masked buffer.
// Finalize is fused via last-block-done: partials -> threadfence -> atomicAdd;
// the last block sums 4096 partials (double) and writes the loss scalar,
// saving the ~3-4us single-block finalize launch.
// ---------------------------------------------------------------------------
__global__ __launch_bounds__(256) void eot_main(
    const float* __restrict__ img, const uint2* __restrict__ msk,
    const float* __restrict__ trans, float* __restrict__ out,
    float* __restrict__ partials, unsigned int* __restrict__ counter,
    float* __restrict__ loss) {
  __shared__ float tr[NNB * 8];
  if (threadIdx.x < NNB * 8) tr[threadIdx.x] = trans[threadIdx.x];
  __syncthreads();

  const int p = blockIdx.x * PIXB + threadIdx.x;
  const int yy = p >> 9;            // W = 512
  const int xx = p & (WW - 1);
  const float fx = (float)xx, fy = (float)yy;
  const int pb = p * 3;

  // per-pixel loads + atanh, amortized over the n-loop
  const float i0 = img[pb], i1 = img[pb + 1], i2 = img[pb + 2];
  const float w0 = 0.5f * logf((1.0f + i0) / (1.0f - i0));
  const float w1 = 0.5f * logf((1.0f + i1) / (1.0f - i1));
  const float w2 = 0.5f * logf((1.0f + i2) / (1.0f - i2));

  const int n0 = blockIdx.y * NPT;
  float accv = 0.0f;

#pragma unroll 2
  for (int k = 0; k < NPT; ++k) {
    const int n = n0 + k;
    const float* t = &tr[n * 8];    // same-address LDS broadcast, conflict-free
    const float a0 = t[0], a1 = t[1], a2 = t[2];
    const float b0 = t[3], b1 = t[4], b2 = t[5];
    const float c0 = t[6], c1 = t[7];

    const float den = c0 * fx + c1 * fy + 1.0f;
    const float rden = __fdividef(1.0f, den);
    const float sx = (a0 * fx + a1 * fy + a2) * rden;
    const float sy = (b0 * fx + b1 * fy + b2) * rden;

    const float x0f = floorf(sx), y0f = floorf(sy);
    const float wx = sx - x0f, wy = sy - y0f;
    const float x1f = x0f + 1.0f, y1f = y0f + 1.0f;

    const bool vx0 = (x0f >= 0.0f) & (x0f <= (float)(WW - 1));
    const bool vx1 = (x1f >= 0.0f) & (x1f <= (float)(WW - 1));
    const bool vy0 = (y0f >= 0.0f) & (y0f <= (float)(HH - 1));
    const bool vy1 = (y1f >= 0.0f) & (y1f <= (float)(HH - 1));

    const int xi0 = min(max((int)x0f, 0), WW - 1);
    const int xi1 = min(max((int)x1f, 0), WW - 1);
    const int yi0 = min(max((int)y0f, 0), HH - 1);
    const int yi1 = min(max((int)y1f, 0), HH - 1);

    const float f00 = (vx0 & vy0) ? 1.0f : 0.0f;
    const float f01 = (vx1 & vy0) ? 1.0f : 0.0f;
    const float f10 = (vx0 & vy1) ? 1.0f : 0.0f;
    const float f11 = (vx1 & vy1) ? 1.0f : 0.0f;

    // one 8B load per tap (fp16-padded layout)
    union cvt_t { uint2 u; __half2 h[2]; };
    cvt_t t00, t01, t10, t11;
    t00.u = msk[yi0 * WW + xi0];
    t01.u = msk[yi0 * WW + xi1];
    t10.u = msk[yi1 * WW + xi0];
    t11.u = msk[yi1 * WW + xi1];

    const float2 l00 = __half22float2(t00.h[0]);
    const float  h00 = __half2float(__low2half(t00.h[1]));
    const float2 l01 = __half22float2(t01.h[0]);
    const float  h01 = __half2float(__low2half(t01.h[1]));
    const float2 l10 = __half22float2(t10.h[0]);
    const float  h10 = __half2float(__low2half(t10.h[1]));
    const float2 l11 = __half22float2(t11.h[0]);
    const float  h11 = __half2float(__low2half(t11.h[1]));

    const float omwx = 1.0f - wx, omwy = 1.0f - wy;
    const float c00 = f00 * omwx * omwy;
    const float c01 = f01 * wx * omwy;
    const float c10 = f10 * omwx * wy;
    const float c11 = f11 * wx * wy;

    const float wp0 = l00.x * c00 + l01.x * c01 + l10.x * c10 + l11.x * c11;
    const float wp1 = l00.y * c00 + l01.y * c01 + l10.y * c10 + l11.y * c11;
    const float wp2 = h00 * c00 + h01 * c01 + h10 * c10 + h11 * c11;

    // tanh(a) = 1 - 2/(e^{2a}+1); |a| < ~2.3 here, err ~2e-7
    const float E0 = __expf(2.0f * (w0 + wp0));
    const float E1 = __expf(2.0f * (w1 + wp1));
    const float E2 = __expf(2.0f * (w2 + wp2));
    const float con0 = 1.0f - __fdividef(2.0f, E0 + 1.0f);
    const float con1 = 1.0f - __fdividef(2.0f, E1 + 1.0f);
    const float con2 = 1.0f - __fdividef(2.0f, E2 + 1.0f);

    float* o = out + (size_t)n * IMG_ELEMS + pb;
    __builtin_nontemporal_store(con0, o);
    __builtin_nontemporal_store(con1, o + 1);
    __builtin_nontemporal_store(con2, o + 2);

    const float p0 = i0 - con0, p1 = i1 - con1, p2 = i2 - con2;
    accv = fmaf(p0, p0, fmaf(p1, p1, fmaf(p2, p2, accv)));
  }

  // block reduction -> one partial per block (no same-address global atomics)
#pragma unroll
  for (int off = 32; off > 0; off >>= 1) accv += __shfl_down(accv, off, 64);
  __shared__ float red[4];
  const int lane = threadIdx.x & 63, wid = threadIdx.x >> 6;
  if (lane == 0) red[wid] = accv;
  __syncthreads();

  __shared__ bool amLast;
  if (threadIdx.x == 0) {
    partials[blockIdx.y * PBLK + blockIdx.x] = red[0] + red[1] + red[2] + red[3];
    __threadfence();                          // partial visible device-wide
    const unsigned int prev = atomicAdd(counter, 1u);
    amLast = (prev == (unsigned int)(NPART - 1));
  }
  __syncthreads();

  // last finished block sums all partials (deterministic order, double accum)
  if (amLast) {
    __threadfence();                          // acquire: see all partials
    double s = 0.0;
    for (int i = threadIdx.x; i < NPART; i += 256) s += (double)partials[i];
#pragma unroll
    for (int off = 32; off > 0; off >>= 1) s += __shfl_down(s, off, 64);
    __shared__ double dred[4];
    if (lane == 0) dred[wid] = s;
    __syncthreads();
    if (threadIdx.x == 0) {
      loss[0] = 0.01f * (float)sqrt(dred[0] + dred[1] + dred[2] + dred[3]);
    }
  }
}

extern "C" void kernel_launch(void* const* d_in, const int* in_sizes, int n_in,
                              void* d_out, int out_size, void* d_ws, size_t ws_size,
                              hipStream_t stream) {
  const float* image = (const float*)d_in[0];
  const float* mask  = (const float*)d_in[1];
  const float* inter = (const float*)d_in[2];
  const float* trans = (const float*)d_in[3];
  float* out = (float*)d_out;

  // ws layout: [masked: 262144 ushort4 = 2MB (8B-aligned at base)]
  //            [partials: 4096 f32][counter: 1 u32]
  ushort4* masked = (ushort4*)d_ws;
  float* partials = (float*)(masked + PIX);
  unsigned int* counter = (unsigned int*)(partials + NPART);

  eot_prep<<<PBLK, 256, 0, stream>>>(mask, inter, masked, counter);

  dim3 grid(PBLK, NSPLIT);
  eot_main<<<grid, PIXB, 0, stream>>>(image, (const uint2*)masked, trans, out,
                                      partials, counter,
                                      out + (size_t)NNB * IMG_ELEMS);
}

// Round 10
// 144.486 us; speedup vs baseline: 1.8882x; 1.8882x over previous
//
#include <hip/hip_runtime.h>
#include <math.h>

// Problem constants (from reference): N=32, H=512, W=512, C=3, fp32 everywhere.
#define HH 512
#define WW 512
#define NNB 32
constexpr int PIXB = 256;                  // threads per block (4 waves)
constexpr int PIX = HH * WW;               // 262144 pixels per image
constexpr int IMG_ELEMS = PIX * 3;         // 786432 floats per [H,W,C] image
constexpr int NSPLIT = 4;                  // n-groups (blockIdx.y); 8 transforms per thread
constexpr int NPT = NNB / NSPLIT;          // transforms per thread loop
constexpr int PBLK = PIX / PIXB;           // 1024 pixel-blocks
constexpr int NPART = PBLK * NSPLIT;       // 4096 partials

// MEASURED-GOOD revert (145.2 us total, round 7).  Round 9's two stacked
// changes (fp16 taps + per-block __threadfence fused finalize) regressed
// eot_main to 175 us (614 GB/s, latency-bound): device-scope fences per
// block force cross-XCD L2 maintenance on gfx950, and the fp16 union
// collapsed VGPR to 24, killing tap-load ILP.  Reverted wholesale.

// ---------------------------------------------------------------------------
// Prep: masked4[p] = float4(mask*inter for c=0..2, 0), 16B-aligned so the main
// kernel's bilinear taps are single dwordx4 loads instead of 3 scalar dwords.
// ---------------------------------------------------------------------------
__global__ __launch_bounds__(256) void eot_prep(
    const float* __restrict__ mask, const float* __restrict__ inter,
    float4* __restrict__ masked4) {
  const int p = blockIdx.x * 256 + threadIdx.x;
  const int b = p * 3;
  masked4[p] = make_float4(mask[b] * inter[b],
                           mask[b + 1] * inter[b + 1],
                           mask[b + 2] * inter[b + 2], 0.0f);
}

// ---------------------------------------------------------------------------
// Main: thread per pixel, loop over NPT transforms (n-loop INSIDE the thread):
// img read + atanh happen once per pixel instead of once per (n,pixel).
// Per (n,pixel) VMEM: 4 tap dwordx4 loads + 3 dword stores.
// ---------------------------------------------------------------------------
__global__ __launch_bounds__(256) void eot_main(
    const float* __restrict__ img, const float4* __restrict__ msk4,
    const float* __restrict__ trans, float* __restrict__ out,
    float* __restrict__ partials) {
  __shared__ float tr[NNB * 8];
  if (threadIdx.x < NNB * 8) tr[threadIdx.x] = trans[threadIdx.x];
  __syncthreads();

  const int p = blockIdx.x * PIXB + threadIdx.x;
  const int yy = p >> 9;            // W = 512
  const int xx = p & (WW - 1);
  const float fx = (float)xx, fy = (float)yy;
  const int pb = p * 3;

  // per-pixel loads + atanh, amortized over the n-loop
  const float i0 = img[pb], i1 = img[pb + 1], i2 = img[pb + 2];
  const float w0 = 0.5f * logf((1.0f + i0) / (1.0f - i0));
  const float w1 = 0.5f * logf((1.0f + i1) / (1.0f - i1));
  const float w2 = 0.5f * logf((1.0f + i2) / (1.0f - i2));

  const int n0 = blockIdx.y * NPT;
  float accv = 0.0f;

#pragma unroll 2
  for (int k = 0; k < NPT; ++k) {
    const int n = n0 + k;
    const float* t = &tr[n * 8];    // same-address LDS broadcast, conflict-free
    const float a0 = t[0], a1 = t[1], a2 = t[2];
    const float b0 = t[3], b1 = t[4], b2 = t[5];
    const float c0 = t[6], c1 = t[7];

    const float den = c0 * fx + c1 * fy + 1.0f;
    const float rden = __fdividef(1.0f, den);
    const float sx = (a0 * fx + a1 * fy + a2) * rden;
    const float sy = (b0 * fx + b1 * fy + b2) * rden;

    const float x0f = floorf(sx), y0f = floorf(sy);
    const float wx = sx - x0f, wy = sy - y0f;
    const float x1f = x0f + 1.0f, y1f = y0f + 1.0f;

    const bool vx0 = (x0f >= 0.0f) & (x0f <= (float)(WW - 1));
    const bool vx1 = (x1f >= 0.0f) & (x1f <= (float)(WW - 1));
    const bool vy0 = (y0f >= 0.0f) & (y0f <= (float)(HH - 1));
    const bool vy1 = (y1f >= 0.0f) & (y1f <= (float)(HH - 1));

    const int xi0 = min(max((int)x0f, 0), WW - 1);
    const int xi1 = min(max((int)x1f, 0), WW - 1);
    const int yi0 = min(max((int)y0f, 0), HH - 1);
    const int yi1 = min(max((int)y1f, 0), HH - 1);

    const float f00 = (vx0 & vy0) ? 1.0f : 0.0f;
    const float f01 = (vx1 & vy0) ? 1.0f : 0.0f;
    const float f10 = (vx0 & vy1) ? 1.0f : 0.0f;
    const float f11 = (vx1 & vy1) ? 1.0f : 0.0f;

    // one 16B load per tap (padded layout)
    const float4 v00 = msk4[yi0 * WW + xi0];
    const float4 v01 = msk4[yi0 * WW + xi1];
    const float4 v10 = msk4[yi1 * WW + xi0];
    const float4 v11 = msk4[yi1 * WW + xi1];

    const float omwx = 1.0f - wx, omwy = 1.0f - wy;
    const float c00 = f00 * omwx * omwy;
    const float c01 = f01 * wx * omwy;
    const float c10 = f10 * omwx * wy;
    const float c11 = f11 * wx * wy;

    const float wp0 = v00.x * c00 + v01.x * c01 + v10.x * c10 + v11.x * c11;
    const float wp1 = v00.y * c00 + v01.y * c01 + v10.y * c10 + v11.y * c11;
    const float wp2 = v00.z * c00 + v01.z * c01 + v10.z * c10 + v11.z * c11;

    // tanh(a) = 1 - 2/(e^{2a}+1); |a| < ~2.3 here, err ~2e-7
    const float E0 = __expf(2.0f * (w0 + wp0));
    const float E1 = __expf(2.0f * (w1 + wp1));
    const float E2 = __expf(2.0f * (w2 + wp2));
    const float con0 = 1.0f - __fdividef(2.0f, E0 + 1.0f);
    const float con1 = 1.0f - __fdividef(2.0f, E1 + 1.0f);
    const float con2 = 1.0f - __fdividef(2.0f, E2 + 1.0f);

    float* o = out + (size_t)n * IMG_ELEMS + pb;
    __builtin_nontemporal_store(con0, o);
    __builtin_nontemporal_store(con1, o + 1);
    __builtin_nontemporal_store(con2, o + 2);

    const float p0 = i0 - con0, p1 = i1 - con1, p2 = i2 - con2;
    accv = fmaf(p0, p0, fmaf(p1, p1, fmaf(p2, p2, accv)));
  }

  // block reduction -> one partial per block (no same-address global atomics)
#pragma unroll
  for (int off = 32; off > 0; off >>= 1) accv += __shfl_down(accv, off, 64);
  __shared__ float red[4];
  const int lane = threadIdx.x & 63, wid = threadIdx.x >> 6;
  if (lane == 0) red[wid] = accv;
  __syncthreads();
  if (threadIdx.x == 0) {
    partials[blockIdx.y * PBLK + blockIdx.x] = red[0] + red[1] + red[2] + red[3];
  }
}

// ---------------------------------------------------------------------------
// Finalize: sum 4096 partials (double accum), loss = 0.01*sqrt(sum).
// non_smoothness is identically 0 (empty [0:-1] slice on the size-1 batch axis).
// Kept as a separate launch: the fused last-block-done variant (round 9)
// cost 150us in per-block device-scope fences on gfx950.
// ---------------------------------------------------------------------------
__global__ __launch_bounds__(1024) void eot_finalize(
    const float* __restrict__ partials, float* __restrict__ loss) {
  double s = 0.0;
  for (int i = threadIdx.x; i < NPART; i += 1024) s += (double)partials[i];
#pragma unroll
  for (int off = 32; off > 0; off >>= 1) s += __shfl_down(s, off, 64);
  __shared__ double red[16];
  const int lane = threadIdx.x & 63, wid = threadIdx.x >> 6;
  if (lane == 0) red[wid] = s;
  __syncthreads();
  if (threadIdx.x == 0) {
    double tot = 0.0;
#pragma unroll
    for (int w = 0; w < 16; ++w) tot += red[w];
    loss[0] = 0.01f * (float)sqrt(tot);
  }
}

extern "C" void kernel_launch(void* const* d_in, const int* in_sizes, int n_in,
                              void* d_out, int out_size, void* d_ws, size_t ws_size,
                              hipStream_t stream) {
  const float* image = (const float*)d_in[0];
  const float* mask  = (const float*)d_in[1];
  const float* inter = (const float*)d_in[2];
  const float* trans = (const float*)d_in[3];
  float* out = (float*)d_out;

  // ws layout: [masked4: 262144 float4 = 4MB (16B-aligned at base)]
  //            [partials: 4096 f32]
  float4* masked4 = (float4*)d_ws;
  float* partials = (float*)(masked4 + PIX);

  eot_prep<<<PBLK, 256, 0, stream>>>(mask, inter, masked4);

  dim3 grid(PBLK, NSPLIT);
  eot_main<<<grid, PIXB, 0, stream>>>(image, masked4, trans, out, partials);

  eot_finalize<<<1, 1024, 0, stream>>>(partials, out + (size_t)NNB * IMG_ELEMS);
}